// Round 5
// baseline (6645.757 us; speedup 1.0000x reference)
//
#include <hip/hip_runtime.h>
#include <math.h>

#define NN      65536
#define KNN     12
#define WIDTH   256
#define GW      192
#define DEPTH   7
#define GLAYERS 4
#define FF      48

// spatial grid for kNN
#define GC    96
#define GC3   884736           // 96^3
#define GLO   (-6.0f)
#define GCW   0.125f           // 12/96
#define GINV  8.0f             // 1/GCW

typedef __attribute__((ext_vector_type(8))) _Float16 half8;
typedef __attribute__((ext_vector_type(4))) _Float16 half4;
typedef __attribute__((ext_vector_type(4))) float    f4;

__device__ __forceinline__ float silu_f(float v) { return v / (1.0f + expf(-v)); }

// ---------------- prep: pack x + |x|^2 as float4 ----------------
__global__ __launch_bounds__(256) void prep_xw_kernel(const float* __restrict__ x,
                                                      float4* __restrict__ xw) {
    int i = blockIdx.x * 256 + threadIdx.x;
    float a = x[3*i], b = x[3*i+1], c = x[3*i+2];
    xw[i] = make_float4(a, b, c, a*a + b*b + c*c);
}

// ---------------- grid build: zero, hist(+rank), scan x3, scatter ----------------
__global__ __launch_bounds__(256) void zero_cnt_kernel(int* __restrict__ cnt) {
    int g = blockIdx.x*256 + threadIdx.x;
    *(int4*)&cnt[g*4] = make_int4(0,0,0,0);
}

__device__ __forceinline__ int cell_of(float v) {
    int c = (int)floorf((v - GLO) * GINV);
    return min(max(c, 0), GC-1);
}

__global__ __launch_bounds__(256) void hist_kernel(const float4* __restrict__ xw,
                                                   int* __restrict__ cnt,
                                                   int* __restrict__ pcell,
                                                   int* __restrict__ prank) {
    int i = blockIdx.x*256 + threadIdx.x;
    float4 p = xw[i];
    int c = (cell_of(p.z)*GC + cell_of(p.y))*GC + cell_of(p.x);
    pcell[i] = c;
    prank[i] = atomicAdd(&cnt[c], 1);
}

__global__ __launch_bounds__(256) void scan1_kernel(const int* __restrict__ cnt,
                                                    int* __restrict__ start,
                                                    int* __restrict__ sums) {
    __shared__ int lds[256];
    const int tid = threadIdx.x;
    int base = blockIdx.x*1024 + tid*4;
    int4 v = *(const int4*)&cnt[base];
    int s0 = v.x, s01 = v.x+v.y, s012 = s01+v.z, tot = s012+v.w;
    lds[tid] = tot; __syncthreads();
    for (int off = 1; off < 256; off <<= 1) {
        int t = (tid >= off) ? lds[tid-off] : 0;
        __syncthreads();
        lds[tid] += t;
        __syncthreads();
    }
    int excl = lds[tid] - tot;
    int4 o; o.x = excl; o.y = excl+s0; o.z = excl+s01; o.w = excl+s012;
    *(int4*)&start[base] = o;
    if (tid == 255) sums[blockIdx.x] = lds[255];
}

__global__ __launch_bounds__(1024) void scan2_kernel(int* __restrict__ sums) {
    __shared__ int lds[1024];
    const int tid = threadIdx.x;
    int v = (tid < 864) ? sums[tid] : 0;
    lds[tid] = v; __syncthreads();
    for (int off = 1; off < 1024; off <<= 1) {
        int t = (tid >= off) ? lds[tid-off] : 0;
        __syncthreads();
        lds[tid] += t;
        __syncthreads();
    }
    if (tid < 864) sums[tid] = lds[tid] - v;   // exclusive
}

__global__ __launch_bounds__(256) void scan3_kernel(int* __restrict__ start,
                                                    const int* __restrict__ sums) {
    int g = blockIdx.x*256 + threadIdx.x;
    start[g] += sums[g >> 10];
}

__global__ __launch_bounds__(256) void scatter_kernel(const float4* __restrict__ xw,
                                                      const int* __restrict__ pcell,
                                                      const int* __restrict__ prank,
                                                      const int* __restrict__ start,
                                                      float4* __restrict__ xs,
                                                      int* __restrict__ sidx) {
    int i = blockIdx.x*256 + threadIdx.x;
    int p = start[pcell[i]] + prank[i];
    xs[p] = xw[i];
    sidx[p] = i;
}

// ---------------- grid kNN query: ring expansion, exact ----------------
__global__ __launch_bounds__(256) void knn_query_kernel(const float4* __restrict__ xs,
                                                        const int* __restrict__ sidx,
                                                        const int* __restrict__ start,
                                                        const int* __restrict__ cnt,
                                                        int* __restrict__ knn_idx) {
    const int gid = blockIdx.x*256 + threadIdx.x;
    const float4 me = xs[gid];              // coalesced: queries in cell-sorted order
    const int q = sidx[gid];
    const float qsq = me.w;
    const int cx = cell_of(me.x), cy = cell_of(me.y), cz = cell_of(me.z);
    float bd[KNN]; int bi[KNN];
#pragma unroll
    for (int k = 0; k < KNN; ++k) { bd[k] = 3e38f; bi[k] = -1; }
    float worst = 3e38f;

    auto scan_cell = [&](int X, int Y, int Z) {
        // min squared distance from me to cell box (boundary cells half-unbounded
        // so clamped outlier points remain covered); +1e-4 margin for fp rounding
        float lox = GLO + X*GCW, loy = GLO + Y*GCW, loz = GLO + Z*GCW;
        float dxl = (X > 0)    ? (lox - me.x)       : -1.f;
        float dxh = (X < GC-1) ? (me.x - lox - GCW) : -1.f;
        float dyl = (Y > 0)    ? (loy - me.y)       : -1.f;
        float dyh = (Y < GC-1) ? (me.y - loy - GCW) : -1.f;
        float dzl = (Z > 0)    ? (loz - me.z)       : -1.f;
        float dzh = (Z < GC-1) ? (me.z - loz - GCW) : -1.f;
        float ddx = fmaxf(0.f, fmaxf(dxl, dxh));
        float ddy = fmaxf(0.f, fmaxf(dyl, dyh));
        float ddz = fmaxf(0.f, fmaxf(dzl, dzh));
        float md = ddx*ddx + ddy*ddy + ddz*ddz;
        if (md >= worst + 1e-4f) return;
        int c = (Z*GC + Y)*GC + X;
        int s = start[c], n = cnt[c];
        for (int t = s; t < s + n; ++t) {
            float4 cc = xs[t];
            float dot = me.x*cc.x + me.y*cc.y + me.z*cc.z;
            float d = fmaf(-2.0f, dot, qsq + cc.w);   // same formula as ref
            if (d < worst) {
                int j = sidx[t];
                if (j != q) {                          // self excluded (ref +1e9)
                    d = fmaxf(d, 0.0f);                // ref clips at 0
                    bd[KNN-1] = d; bi[KNN-1] = j;
#pragma unroll
                    for (int k = KNN-1; k > 0; --k) {
                        if (bd[k] < bd[k-1]) {
                            float td = bd[k]; bd[k] = bd[k-1]; bd[k-1] = td;
                            int   ti = bi[k]; bi[k] = bi[k-1]; bi[k-1] = ti;
                        }
                    }
                    worst = bd[KNN-1];
                }
            }
        }
    };

    for (int R = 0; R < GC; ++R) {
        if (R >= 1) {
            // unscanned cells are at Chebyshev >= R: min dist >= (R-1)*GCW
            float bnd = (R-1) * GCW;
            if (worst + 1e-4f <= bnd*bnd) break;   // worst<3e38 => 12 found
        }
        int z0 = max(cz-R, 0), z1 = min(cz+R, GC-1);
        int y0 = max(cy-R, 0), y1 = min(cy+R, GC-1);
        int x0 = max(cx-R, 0), x1 = min(cx+R, GC-1);
        for (int z = z0; z <= z1; ++z) {
            int az = abs(z - cz);
            for (int y = y0; y <= y1; ++y) {
                int m2 = max(az, abs(y - cy));
                if (m2 == R) {
                    for (int xx = x0; xx <= x1; ++xx) scan_cell(xx, y, z);
                } else {
                    if (cx-R >= 0)    scan_cell(cx-R, y, z);
                    if (cx+R <= GC-1) scan_cell(cx+R, y, z);
                }
            }
        }
    }
#pragma unroll
    for (int k = 0; k < KNN; ++k) knn_idx[q*KNN + k] = bi[k];
}

// ---------------- weight convert+transpose to f16 [N][K] ----------------
__global__ __launch_bounds__(256) void convert_Wt_kernel(const float* __restrict__ W,
                                                         _Float16* __restrict__ Wt) {
    int e = blockIdx.x*256 + threadIdx.x;          // over DEPTH*65536
    int l = e >> 16, r = e & 65535;
    int n = r >> 8, k = r & 255;
    Wt[(size_t)l*65536 + n*256 + k] = (_Float16)W[(size_t)l*65536 + k*256 + n];
}

__global__ __launch_bounds__(256) void convert_Bg_kernel(const float* __restrict__ Ws,
                                                         const float* __restrict__ Wn,
                                                         _Float16* __restrict__ Bg) {
    int e = blockIdx.x*256 + threadIdx.x;          // over GLAYERS*192*384
    int l = e / 73728, r = e % 73728;
    int n = r / 384, k = r % 384;
    float v = (k < 192) ? Ws[(size_t)l*36864 + k*192 + n]
                        : Wn[(size_t)l*36864 + (k-192)*192 + n];
    Bg[(size_t)l*73728 + (size_t)n*384 + k] = (_Float16)v;
}

__global__ __launch_bounds__(256) void convert_Wgo_kernel(const float* __restrict__ Wg_out,
                                                          _Float16* __restrict__ Wgo) {
    int e = blockIdx.x*256 + threadIdx.x;          // over 256*192
    int n = e / 192, k = e % 192;
    Wgo[e] = (_Float16)Wg_out[k*256 + n];
}

// ---------------- fourier features + both input layers (f16 out) ----------------
__global__ __launch_bounds__(256) void fourier_input_kernel(
    const float* __restrict__ x, const float* __restrict__ Bf,
    const float* __restrict__ W_in, const float* __restrict__ b_in,
    const float* __restrict__ Wg_in, const float* __restrict__ bg_in,
    _Float16* __restrict__ h0, _Float16* __restrict__ g0) {
    const int n = blockIdx.x * 256 + threadIdx.x;
    const float x0 = x[3*n], x1 = x[3*n+1], x2 = x[3*n+2];
    float ff[FF];
#pragma unroll
    for (int sm = 0; sm < 24; ++sm) {
        int s = sm >> 3, m = sm & 7;
        float p = x0*Bf[s*24 + m] + x1*Bf[s*24 + 8 + m] + x2*Bf[s*24 + 16 + m];
        float sv, cv; sincosf(p, &sv, &cv);
        ff[sm] = sv; ff[24 + sm] = cv;
    }
    {
        const float4* W4 = (const float4*)W_in;
        const float4* b4 = (const float4*)b_in;
#pragma unroll 2
        for (int j4 = 0; j4 < WIDTH/4; ++j4) {
            float4 acc = b4[j4];
#pragma unroll
            for (int k = 0; k < FF; ++k) {
                float4 w = W4[k*(WIDTH/4) + j4]; float f = ff[k];
                acc.x = fmaf(f, w.x, acc.x); acc.y = fmaf(f, w.y, acc.y);
                acc.z = fmaf(f, w.z, acc.z); acc.w = fmaf(f, w.w, acc.w);
            }
            half4 o;
            o[0] = (_Float16)silu_f(acc.x); o[1] = (_Float16)silu_f(acc.y);
            o[2] = (_Float16)silu_f(acc.z); o[3] = (_Float16)silu_f(acc.w);
            *(half4*)&h0[(size_t)n*WIDTH + j4*4] = o;
        }
    }
    {
        const float4* W4 = (const float4*)Wg_in;
        const float4* b4 = (const float4*)bg_in;
#pragma unroll 2
        for (int j4 = 0; j4 < GW/4; ++j4) {
            float4 acc = b4[j4];
#pragma unroll
            for (int k = 0; k < FF; ++k) {
                float4 w = W4[k*(GW/4) + j4]; float f = ff[k];
                acc.x = fmaf(f, w.x, acc.x); acc.y = fmaf(f, w.y, acc.y);
                acc.z = fmaf(f, w.z, acc.z); acc.w = fmaf(f, w.w, acc.w);
            }
            half4 o;
            o[0] = (_Float16)silu_f(acc.x); o[1] = (_Float16)silu_f(acc.y);
            o[2] = (_Float16)silu_f(acc.z); o[3] = (_Float16)silu_f(acc.w);
            *(half4*)&g0[(size_t)n*GW + j4*4] = o;
        }
    }
}

// ---------------- gather + mean over 12 neighbors (f16) ----------------
__global__ __launch_bounds__(192) void gather_mean_kernel(const _Float16* __restrict__ g,
                                                          const int* __restrict__ idx,
                                                          _Float16* __restrict__ agg) {
    __shared__ int nb[KNN];
    const int n = blockIdx.x;
    if (threadIdx.x < KNN) nb[threadIdx.x] = idx[n*KNN + threadIdx.x];
    __syncthreads();
    float acc = 0.0f;
#pragma unroll
    for (int k = 0; k < KNN; ++k) acc += (float)g[(size_t)nb[k]*GW + threadIdx.x];
    agg[(size_t)n*GW + threadIdx.x] = (_Float16)(acc * (1.0f/12.0f));
}

// ---------------- FiLM params ----------------
__global__ __launch_bounds__(256) void film_kernel(const float* __restrict__ cond,
                                                   const float* __restrict__ Wf_g,
                                                   const float* __restrict__ bf_g,
                                                   const float* __restrict__ Wf_b,
                                                   const float* __restrict__ bf_b,
                                                   float* __restrict__ film) {
    const int l = blockIdx.x, j = threadIdx.x;
    float g = bf_g[l*WIDTH + j], b = bf_b[l*WIDTH + j];
    for (int c = 0; c < 64; ++c) {
        float cv = cond[c];
        g = fmaf(cv, Wf_g[(size_t)(l*64 + c)*WIDTH + j], g);
        b = fmaf(cv, Wf_b[(size_t)(l*64 + c)*WIDTH + j], b);
    }
    film[l*2*WIDTH + j]         = 1.0f + g;
    film[l*2*WIDTH + WIDTH + j] = b;
}

// ---------------- f16 MFMA GEMM: BM=128, BN=64, 4 waves ----------------
template<int EPI>
__global__ __launch_bounds__(256) void gemm_mfma(
    const _Float16* __restrict__ A1, const _Float16* __restrict__ A2,
    const _Float16* __restrict__ Bt, int K1, int Ktot, int NC,
    const float* __restrict__ bias, const float* __restrict__ film,
    const _Float16* __restrict__ h0, _Float16* __restrict__ C, int addSkip) {
    __shared__ _Float16 As[128*40];
    __shared__ _Float16 Bs[64*40];
    const int tid = threadIdx.x;
    const int bm = blockIdx.x * 128, bn = blockIdx.y * 64;
    const int wid = tid >> 6, lane = tid & 63;
    const int wm = (wid & 1) * 64, wn = (wid >> 1) * 32;
    const int m16 = lane & 15, kq = lane >> 4;
    const int ar = tid >> 1, ah = tid & 1;
    const int br = tid >> 2, bq = tid & 3;
    f4 acc[4][2];
#pragma unroll
    for (int i = 0; i < 4; ++i)
#pragma unroll
        for (int j = 0; j < 2; ++j) acc[i][j] = (f4){0.f, 0.f, 0.f, 0.f};

    for (int kc = 0; kc < Ktot; kc += 32) {
        const _Float16* Asrc; int kl, ldA;
        if (kc < K1) { Asrc = A1; kl = kc;      ldA = K1; }
        else         { Asrc = A2; kl = kc - K1; ldA = Ktot - K1; }
        {
            const float4* src = (const float4*)&Asrc[(size_t)(bm + ar)*ldA + kl + ah*16];
            *(float4*)&As[ar*40 + ah*16]     = src[0];
            *(float4*)&As[ar*40 + ah*16 + 8] = src[1];
        }
        *(float4*)&Bs[br*40 + bq*8] = *(const float4*)&Bt[(size_t)(bn + br)*Ktot + kc + bq*8];
        __syncthreads();
        half8 af[4], bf[2];
#pragma unroll
        for (int mt = 0; mt < 4; ++mt) af[mt] = *(half8*)&As[(wm + mt*16 + m16)*40 + kq*8];
#pragma unroll
        for (int nt = 0; nt < 2; ++nt) bf[nt] = *(half8*)&Bs[(wn + nt*16 + m16)*40 + kq*8];
#pragma unroll
        for (int mt = 0; mt < 4; ++mt)
#pragma unroll
            for (int nt = 0; nt < 2; ++nt)
                acc[mt][nt] = __builtin_amdgcn_mfma_f32_16x16x32_f16(af[mt], bf[nt], acc[mt][nt], 0, 0, 0);
        __syncthreads();
    }

#pragma unroll
    for (int mt = 0; mt < 4; ++mt) {
#pragma unroll
        for (int nt = 0; nt < 2; ++nt) {
            int col = bn + wn + nt*16 + m16;
#pragma unroll
            for (int r = 0; r < 4; ++r) {
                int row = bm + wm + mt*16 + kq*4 + r;
                float v = acc[mt][nt][r];
                if (EPI == 0) {
                    v = silu_f(v + bias[col]);
                } else if (EPI == 1) {
                    v = fmaf(v + bias[col], film[col], film[NC + col]);
                    v = silu_f(v);
                    if (addSkip) v += (float)h0[(size_t)row*NC + col];
                } else {
                    v += (float)h0[(size_t)row*NC + col];
                }
                C[(size_t)row*NC + col] = (_Float16)v;
            }
        }
    }
}

// ---------------- output head: (h @ W_out + b_out) * 0.01 ----------------
__global__ __launch_bounds__(256) void out_kernel(const _Float16* __restrict__ h,
                                                  const float* __restrict__ W_out,
                                                  const float* __restrict__ b_out,
                                                  float* __restrict__ out) {
    const int n = blockIdx.x * 256 + threadIdx.x;
    float a0 = 0.f, a1 = 0.f, a2 = 0.f;
#pragma unroll 4
    for (int k8 = 0; k8 < WIDTH/8; ++k8) {
        half8 v = *(const half8*)&h[(size_t)n*WIDTH + k8*8];
#pragma unroll
        for (int u = 0; u < 8; ++u) {
            float f = (float)v[u]; int k = k8*8 + u;
            a0 = fmaf(f, W_out[k*3+0], a0);
            a1 = fmaf(f, W_out[k*3+1], a1);
            a2 = fmaf(f, W_out[k*3+2], a2);
        }
    }
    out[n*3+0] = (a0 + b_out[0]) * 0.01f;
    out[n*3+1] = (a1 + b_out[1]) * 0.01f;
    out[n*3+2] = (a2 + b_out[2]) * 0.01f;
}

extern "C" void kernel_launch(void* const* d_in, const int* in_sizes, int n_in,
                              void* d_out, int out_size, void* d_ws, size_t ws_size,
                              hipStream_t stream) {
    const float* x      = (const float*)d_in[0];
    const float* cond   = (const float*)d_in[1];
    const float* Bf     = (const float*)d_in[2];
    const float* W_in   = (const float*)d_in[3];
    const float* b_in   = (const float*)d_in[4];
    const float* Wg_in  = (const float*)d_in[5];
    const float* bg_in  = (const float*)d_in[6];
    const float* Ws     = (const float*)d_in[7];
    const float* Wn     = (const float*)d_in[8];
    const float* bg     = (const float*)d_in[9];
    const float* Wg_out = (const float*)d_in[10];
    const float* W      = (const float*)d_in[11];
    const float* bmlp   = (const float*)d_in[12];
    const float* Wf_g   = (const float*)d_in[13];
    const float* bf_g   = (const float*)d_in[14];
    const float* Wf_b   = (const float*)d_in[15];
    const float* bf_b   = (const float*)d_in[16];
    const float* W_out  = (const float*)d_in[17];
    const float* b_out  = (const float*)d_in[18];
    float* out = (float*)d_out;

    char* ws = (char*)d_ws;
    int*       knn_idx = (int*)      (ws + 0);          //  3,145,728
    float4*    xw      = (float4*)   (ws + 3145728);    //  1,048,576
    float*     film    = (float*)    (ws + 4194304);    //     14,336
    _Float16*  Bg_t    = (_Float16*) (ws + 4210688);    //    589,824
    _Float16*  Wgo_t   = (_Float16*) (ws + 4800512);    //     98,304
    _Float16*  Wt      = (_Float16*) (ws + 4898816);    //    917,504
    _Float16*  h0      = (_Float16*) (ws + 5816320);    // 33,554,432 (f16)
    // grid-kNN scratch overlays h0 region (dead before fourier_input writes h0)
    char*      gb      = ws + 5816320;
    int*       cnt     = (int*)      (gb + 0);          // 3,538,944
    int*       cstart  = (int*)      (gb + 3538944);    // 3,538,944
    int*       sums    = (int*)      (gb + 7077888);    //     4,096
    int*       pcell   = (int*)      (gb + 7081984);    //   262,144
    int*       prank   = (int*)      (gb + 7344128);    //   262,144
    float4*    xs      = (float4*)   (gb + 7606272);    // 1,048,576
    int*       sidx    = (int*)      (gb + 8654848);    //   262,144 -> 8.92 MB < 33.5 MB
    _Float16*  g_a     = (_Float16*) (ws + 39370752);   // 25,165,824
    _Float16*  g_b     = (_Float16*) (ws + 64536576);   // 25,165,824
    _Float16*  agg     = (_Float16*) (ws + 89702400);   // 25,165,824
    _Float16*  hA      = (_Float16*) (ws + 114868224);  // 33,554,432
    _Float16*  hB      = (_Float16*) (ws + 148422656);  // 33,554,432 -> ends 181,977,088

    // --- grid kNN ---
    prep_xw_kernel<<<NN/256, 256, 0, stream>>>(x, xw);
    zero_cnt_kernel<<<GC3/1024, 256, 0, stream>>>(cnt);
    hist_kernel<<<NN/256, 256, 0, stream>>>(xw, cnt, pcell, prank);
    scan1_kernel<<<GC3/1024, 256, 0, stream>>>(cnt, cstart, sums);
    scan2_kernel<<<1, 1024, 0, stream>>>(sums);
    scan3_kernel<<<GC3/256, 256, 0, stream>>>(cstart, sums);
    scatter_kernel<<<NN/256, 256, 0, stream>>>(xw, pcell, prank, cstart, xs, sidx);
    knn_query_kernel<<<NN/256, 256, 0, stream>>>(xs, sidx, cstart, cnt, knn_idx);

    // --- network ---
    film_kernel<<<DEPTH, 256, 0, stream>>>(cond, Wf_g, bf_g, Wf_b, bf_b, film);
    convert_Wt_kernel<<<DEPTH*65536/256, 256, 0, stream>>>(W, Wt);
    convert_Bg_kernel<<<GLAYERS*73728/256, 256, 0, stream>>>(Ws, Wn, Bg_t);
    convert_Wgo_kernel<<<256*192/256, 256, 0, stream>>>(Wg_out, Wgo_t);
    fourier_input_kernel<<<NN/256, 256, 0, stream>>>(x, Bf, W_in, b_in, Wg_in, bg_in, h0, g_a);

    _Float16* gin = g_a; _Float16* gout = g_b;
    for (int l = 0; l < GLAYERS; ++l) {
        gather_mean_kernel<<<NN, GW, 0, stream>>>(gin, knn_idx, agg);
        gemm_mfma<0><<<dim3(NN/128, GW/64), 256, 0, stream>>>(
            gin, agg, Bg_t + (size_t)l*73728, GW, 2*GW, GW,
            bg + l*GW, nullptr, nullptr, gout, 0);
        _Float16* t = gin; gin = gout; gout = t;
    }
    // gin == g_a (4 swaps). inject: hA = h0 + gin @ Wg_out
    gemm_mfma<2><<<dim3(NN/128, WIDTH/64), 256, 0, stream>>>(
        gin, nullptr, Wgo_t, GW, GW, WIDTH, nullptr, nullptr, h0, hA, 0);

    _Float16* hin = hA; _Float16* hout = hB;
    for (int l = 0; l < DEPTH; ++l) {
        int skip = (l == 2 || l == 5) ? 1 : 0;   // SKIPS=(3,6): after layers idx 2,5
        gemm_mfma<1><<<dim3(NN/128, WIDTH/64), 256, 0, stream>>>(
            hin, nullptr, Wt + (size_t)l*65536, WIDTH, WIDTH, WIDTH,
            bmlp + l*WIDTH, film + l*2*WIDTH, h0, hout, skip);
        _Float16* t = hin; hin = hout; hout = t;
    }
    out_kernel<<<NN/256, 256, 0, stream>>>(hin, W_out, b_out, out);
}

// Round 6
// 2416.016 us; speedup vs baseline: 2.7507x; 2.7507x over previous
//
#include <hip/hip_runtime.h>
#include <math.h>

#define NN      65536
#define KNN     12
#define WIDTH   256
#define GW      192
#define DEPTH   7
#define GLAYERS 4
#define FF      48

#define KSEG    4            // knn split-K segments
#define SEGLEN  (NN/KSEG)    // 16384 candidates per segment
#define TILE    512          // LDS candidate tile (float4) = 8 KB
#define QCAP    16           // per-lane deferral queue capacity (32 KB)
#define QTRIG   8            // flush when any lane count >= QTRIG (batch adds <=8)

// seed grid (SAT): 192^3 cells over [-6,6]^3, cell 0.0625
#define GC    192
#define GC3   7077888
#define GLO   (-6.0f)
#define GCW   0.0625f
#define GINV  16.0f

typedef __attribute__((ext_vector_type(8))) _Float16 half8;
typedef __attribute__((ext_vector_type(4))) _Float16 half4;
typedef __attribute__((ext_vector_type(4))) float    f4;

__device__ __forceinline__ float silu_f(float v) { return v / (1.0f + expf(-v)); }

// ---------------- prep: pack x + |x|^2 as float4 ----------------
__global__ __launch_bounds__(256) void prep_xw_kernel(const float* __restrict__ x,
                                                      float4* __restrict__ xw) {
    int i = blockIdx.x * 256 + threadIdx.x;
    float a = x[3*i], b = x[3*i+1], c = x[3*i+2];
    xw[i] = make_float4(a, b, c, a*a + b*b + c*c);
}

// ---------------- seed grid: zero, hist, 3-pass in-place SAT, per-query bound ----------------
__global__ __launch_bounds__(256) void zero_cnt_kernel(int* __restrict__ cnt) {
    int g = blockIdx.x*256 + threadIdx.x;
    *(int4*)&cnt[g*4] = make_int4(0,0,0,0);
}

__device__ __forceinline__ int cell_of(float v) {
    int c = (int)floorf((v - GLO) * GINV);
    return min(max(c, 0), GC-1);
}

__global__ __launch_bounds__(256) void hist_kernel(const float4* __restrict__ xw,
                                                   int* __restrict__ cnt) {
    int i = blockIdx.x*256 + threadIdx.x;
    float4 p = xw[i];
    atomicAdd(&cnt[(cell_of(p.z)*GC + cell_of(p.y))*GC + cell_of(p.x)], 1);
}

__global__ __launch_bounds__(256) void satx_kernel(int* __restrict__ S) {
    int zy = blockIdx.x*256 + threadIdx.x;     // 36864 lines, x contiguous
    int base = zy * GC, run = 0;
    for (int i = 0; i < GC; ++i) { run += S[base+i]; S[base+i] = run; }
}
__global__ __launch_bounds__(256) void saty_kernel(int* __restrict__ S) {
    int t = blockIdx.x*256 + threadIdx.x;      // (z,x): lanes x-adjacent -> coalesced
    int z = t / GC, xx = t % GC, run = 0;
    for (int y = 0; y < GC; ++y) { int idx = (z*GC + y)*GC + xx; run += S[idx]; S[idx] = run; }
}
__global__ __launch_bounds__(256) void satz_kernel(int* __restrict__ S) {
    int t = blockIdx.x*256 + threadIdx.x;      // (y,x): lanes x-adjacent -> coalesced
    int y = t / GC, xx = t % GC, run = 0;
    for (int z = 0; z < GC; ++z) { int idx = (z*GC + y)*GC + xx; run += S[idx]; S[idx] = run; }
}

__device__ __forceinline__ int satv(const int* __restrict__ S, int xx, int y, int z) {
    if (xx < 0 || y < 0 || z < 0) return 0;
    return S[(z*GC + y)*GC + xx];
}

// seed[q] = guaranteed upper bound on 12-NN squared distance (>=13 pts incl self in box)
__global__ __launch_bounds__(256) void seed_kernel(const float4* __restrict__ xw,
                                                   const int* __restrict__ S,
                                                   float* __restrict__ seed) {
    int q = blockIdx.x*256 + threadIdx.x;
    float4 me = xw[q];
    int cx = cell_of(me.x), cy = cell_of(me.y), cz = cell_of(me.z);
    for (int R = 1; R < GC; ++R) {
        int x0 = max(cx-R, 0), x1 = min(cx+R, GC-1);
        int y0 = max(cy-R, 0), y1 = min(cy+R, GC-1);
        int z0 = max(cz-R, 0), z1 = min(cz+R, GC-1);
        int c = satv(S,x1,y1,z1) - satv(S,x0-1,y1,z1) - satv(S,x1,y0-1,z1) - satv(S,x1,y1,z0-1)
              + satv(S,x0-1,y0-1,z1) + satv(S,x0-1,y1,z0-1) + satv(S,x1,y0-1,z0-1)
              - satv(S,x0-1,y0-1,z0-1);
        if (c >= KNN + 1) {
            // exact farthest-corner distance from me to the (clamped) box
            float dx = fmaxf(me.x - (GLO + x0*GCW), (GLO + (x1+1)*GCW) - me.x);
            float dy = fmaxf(me.y - (GLO + y0*GCW), (GLO + (y1+1)*GCW) - me.y);
            float dz = fmaxf(me.z - (GLO + z0*GCW), (GLO + (z1+1)*GCW) - me.z);
            seed[q] = (dx*dx + dy*dy + dz*dz) * 1.00002f + 1e-6f;
            return;
        }
    }
    seed[q] = 3e38f;
}

// ---------------- kNN split-K scan, seeded worst + per-lane LDS deferral queue ----------------
__device__ __forceinline__ void knn_flush(float2* qbuf, int tid, int& cnt, float seedv,
                                          float bd[KNN], int bi[KNN], float& worst) {
    int p = 0;
    while (__any(p < cnt)) {
        if (p < cnt) {
            float2 e = qbuf[p*256 + tid];
            float d = e.x;
            if (d < bd[KNN-1]) {
                bd[KNN-1] = d; bi[KNN-1] = __float_as_int(e.y);
#pragma unroll
                for (int k = KNN-1; k > 0; --k) {
                    if (bd[k] < bd[k-1]) {
                        float td = bd[k]; bd[k] = bd[k-1]; bd[k-1] = td;
                        int   ti = bi[k]; bi[k] = bi[k-1]; bi[k-1] = ti;
                    }
                }
            }
        }
        ++p;
    }
    cnt = 0;
    worst = fminf(bd[KNN-1], seedv);
}

__global__ __launch_bounds__(256) void knn_part_kernel(const float4* __restrict__ xw,
                                                       const float* __restrict__ seed,
                                                       float* __restrict__ pd,
                                                       int* __restrict__ pi) {
    __shared__ float4 tile[TILE];
    __shared__ float2 qbuf[QCAP*256];
    const int tid = threadIdx.x;
    const int q   = blockIdx.x * 256 + tid;
    const int seg = blockIdx.y;
    const float4 me = xw[q];
    const float qsq = me.w;
    const float seedv = seed[q];
    float bd[KNN]; int bi[KNN];
#pragma unroll
    for (int k = 0; k < KNN; ++k) { bd[k] = 3e38f; bi[k] = -1; }
    float worst = seedv;
    int cnt = 0;

    for (int t0 = seg*SEGLEN; t0 < (seg+1)*SEGLEN; t0 += TILE) {
        __syncthreads();
        tile[tid]       = xw[t0 + tid];
        tile[tid + 256] = xw[t0 + 256 + tid];
        __syncthreads();
        for (int b = 0; b < TILE; b += 8) {
            if (__any(cnt >= QTRIG)) knn_flush(qbuf, tid, cnt, seedv, bd, bi, worst);
            float d[8];
#pragma unroll
            for (int u = 0; u < 8; ++u) {
                float4 c = tile[b + u];
                float dot = me.x*c.x + me.y*c.y + me.z*c.z;
                d[u] = fmaf(-2.0f, dot, qsq + c.w);   // same formula as ref
            }
            float m01 = fminf(d[0],d[1]), m23 = fminf(d[2],d[3]);
            float m45 = fminf(d[4],d[5]), m67 = fminf(d[6],d[7]);
            float mn = fminf(fminf(m01,m23), fminf(m45,m67));
            if (mn < worst) {
#pragma unroll
                for (int u = 0; u < 8; ++u) {
                    if (d[u] < worst) {
                        int gj = t0 + b + u;
                        if (gj != q) {
                            float dc = fmaxf(d[u], 0.0f);
                            qbuf[cnt*256 + tid] = make_float2(dc, __int_as_float(gj));
                            ++cnt;
                        }
                    }
                }
            }
        }
    }
    knn_flush(qbuf, tid, cnt, seedv, bd, bi, worst);
#pragma unroll
    for (int k = 0; k < KNN; ++k) {
        pd[(q*KSEG + seg)*KNN + k] = bd[k];
        pi[(q*KSEG + seg)*KNN + k] = bi[k];
    }
}

__global__ __launch_bounds__(256) void knn_merge_kernel(const float* __restrict__ pd,
                                                        const int* __restrict__ pi,
                                                        int* __restrict__ knn_idx) {
    const int q = blockIdx.x * 256 + threadIdx.x;
    float bd[KNN]; int bi[KNN];
#pragma unroll
    for (int k = 0; k < KNN; ++k) { bd[k] = pd[q*KSEG*KNN + k]; bi[k] = pi[q*KSEG*KNN + k]; }
#pragma unroll
    for (int s = 1; s < KSEG; ++s) {
        for (int k = 0; k < KNN; ++k) {
            float d = pd[(q*KSEG + s)*KNN + k];
            if (d >= bd[KNN-1]) break;      // segment lists sorted ascending
            int gi = pi[(q*KSEG + s)*KNN + k];
            bd[KNN-1] = d; bi[KNN-1] = gi;
#pragma unroll
            for (int t = KNN-1; t > 0; --t) {
                if (bd[t] < bd[t-1]) {
                    float td = bd[t]; bd[t] = bd[t-1]; bd[t-1] = td;
                    int   ti = bi[t]; bi[t] = bi[t-1]; bi[t-1] = ti;
                }
            }
        }
    }
#pragma unroll
    for (int k = 0; k < KNN; ++k) knn_idx[q*KNN + k] = bi[k];
}

// ---------------- weight convert+transpose to f16 [N][K] ----------------
__global__ __launch_bounds__(256) void convert_Wt_kernel(const float* __restrict__ W,
                                                         _Float16* __restrict__ Wt) {
    int e = blockIdx.x*256 + threadIdx.x;
    int l = e >> 16, r = e & 65535;
    int n = r >> 8, k = r & 255;
    Wt[(size_t)l*65536 + n*256 + k] = (_Float16)W[(size_t)l*65536 + k*256 + n];
}

__global__ __launch_bounds__(256) void convert_Bg_kernel(const float* __restrict__ Ws,
                                                         const float* __restrict__ Wn,
                                                         _Float16* __restrict__ Bg) {
    int e = blockIdx.x*256 + threadIdx.x;
    int l = e / 73728, r = e % 73728;
    int n = r / 384, k = r % 384;
    float v = (k < 192) ? Ws[(size_t)l*36864 + k*192 + n]
                        : Wn[(size_t)l*36864 + (k-192)*192 + n];
    Bg[(size_t)l*73728 + (size_t)n*384 + k] = (_Float16)v;
}

__global__ __launch_bounds__(256) void convert_Wgo_kernel(const float* __restrict__ Wg_out,
                                                          _Float16* __restrict__ Wgo) {
    int e = blockIdx.x*256 + threadIdx.x;
    int n = e / 192, k = e % 192;
    Wgo[e] = (_Float16)Wg_out[k*256 + n];
}

// ---------------- fourier features + both input layers (f16 out) ----------------
__global__ __launch_bounds__(256) void fourier_input_kernel(
    const float* __restrict__ x, const float* __restrict__ Bf,
    const float* __restrict__ W_in, const float* __restrict__ b_in,
    const float* __restrict__ Wg_in, const float* __restrict__ bg_in,
    _Float16* __restrict__ h0, _Float16* __restrict__ g0) {
    const int n = blockIdx.x * 256 + threadIdx.x;
    const float x0 = x[3*n], x1 = x[3*n+1], x2 = x[3*n+2];
    float ff[FF];
#pragma unroll
    for (int sm = 0; sm < 24; ++sm) {
        int s = sm >> 3, m = sm & 7;
        float p = x0*Bf[s*24 + m] + x1*Bf[s*24 + 8 + m] + x2*Bf[s*24 + 16 + m];
        float sv, cv; sincosf(p, &sv, &cv);
        ff[sm] = sv; ff[24 + sm] = cv;
    }
    {
        const float4* W4 = (const float4*)W_in;
        const float4* b4 = (const float4*)b_in;
#pragma unroll 2
        for (int j4 = 0; j4 < WIDTH/4; ++j4) {
            float4 acc = b4[j4];
#pragma unroll
            for (int k = 0; k < FF; ++k) {
                float4 w = W4[k*(WIDTH/4) + j4]; float f = ff[k];
                acc.x = fmaf(f, w.x, acc.x); acc.y = fmaf(f, w.y, acc.y);
                acc.z = fmaf(f, w.z, acc.z); acc.w = fmaf(f, w.w, acc.w);
            }
            half4 o;
            o[0] = (_Float16)silu_f(acc.x); o[1] = (_Float16)silu_f(acc.y);
            o[2] = (_Float16)silu_f(acc.z); o[3] = (_Float16)silu_f(acc.w);
            *(half4*)&h0[(size_t)n*WIDTH + j4*4] = o;
        }
    }
    {
        const float4* W4 = (const float4*)Wg_in;
        const float4* b4 = (const float4*)bg_in;
#pragma unroll 2
        for (int j4 = 0; j4 < GW/4; ++j4) {
            float4 acc = b4[j4];
#pragma unroll
            for (int k = 0; k < FF; ++k) {
                float4 w = W4[k*(GW/4) + j4]; float f = ff[k];
                acc.x = fmaf(f, w.x, acc.x); acc.y = fmaf(f, w.y, acc.y);
                acc.z = fmaf(f, w.z, acc.z); acc.w = fmaf(f, w.w, acc.w);
            }
            half4 o;
            o[0] = (_Float16)silu_f(acc.x); o[1] = (_Float16)silu_f(acc.y);
            o[2] = (_Float16)silu_f(acc.z); o[3] = (_Float16)silu_f(acc.w);
            *(half4*)&g0[(size_t)n*GW + j4*4] = o;
        }
    }
}

// ---------------- gather + mean over 12 neighbors (f16) ----------------
__global__ __launch_bounds__(192) void gather_mean_kernel(const _Float16* __restrict__ g,
                                                          const int* __restrict__ idx,
                                                          _Float16* __restrict__ agg) {
    __shared__ int nb[KNN];
    const int n = blockIdx.x;
    if (threadIdx.x < KNN) nb[threadIdx.x] = idx[n*KNN + threadIdx.x];
    __syncthreads();
    float acc = 0.0f;
#pragma unroll
    for (int k = 0; k < KNN; ++k) acc += (float)g[(size_t)nb[k]*GW + threadIdx.x];
    agg[(size_t)n*GW + threadIdx.x] = (_Float16)(acc * (1.0f/12.0f));
}

// ---------------- FiLM params ----------------
__global__ __launch_bounds__(256) void film_kernel(const float* __restrict__ cond,
                                                   const float* __restrict__ Wf_g,
                                                   const float* __restrict__ bf_g,
                                                   const float* __restrict__ Wf_b,
                                                   const float* __restrict__ bf_b,
                                                   float* __restrict__ film) {
    const int l = blockIdx.x, j = threadIdx.x;
    float g = bf_g[l*WIDTH + j], b = bf_b[l*WIDTH + j];
    for (int c = 0; c < 64; ++c) {
        float cv = cond[c];
        g = fmaf(cv, Wf_g[(size_t)(l*64 + c)*WIDTH + j], g);
        b = fmaf(cv, Wf_b[(size_t)(l*64 + c)*WIDTH + j], b);
    }
    film[l*2*WIDTH + j]         = 1.0f + g;
    film[l*2*WIDTH + WIDTH + j] = b;
}

// ---------------- f16 MFMA GEMM: BM=128, BN=64, 4 waves ----------------
template<int EPI>
__global__ __launch_bounds__(256) void gemm_mfma(
    const _Float16* __restrict__ A1, const _Float16* __restrict__ A2,
    const _Float16* __restrict__ Bt, int K1, int Ktot, int NC,
    const float* __restrict__ bias, const float* __restrict__ film,
    const _Float16* __restrict__ h0, _Float16* __restrict__ C, int addSkip) {
    __shared__ _Float16 As[128*40];
    __shared__ _Float16 Bs[64*40];
    const int tid = threadIdx.x;
    const int bm = blockIdx.x * 128, bn = blockIdx.y * 64;
    const int wid = tid >> 6, lane = tid & 63;
    const int wm = (wid & 1) * 64, wn = (wid >> 1) * 32;
    const int m16 = lane & 15, kq = lane >> 4;
    const int ar = tid >> 1, ah = tid & 1;
    const int br = tid >> 2, bq = tid & 3;
    f4 acc[4][2];
#pragma unroll
    for (int i = 0; i < 4; ++i)
#pragma unroll
        for (int j = 0; j < 2; ++j) acc[i][j] = (f4){0.f, 0.f, 0.f, 0.f};

    for (int kc = 0; kc < Ktot; kc += 32) {
        const _Float16* Asrc; int kl, ldA;
        if (kc < K1) { Asrc = A1; kl = kc;      ldA = K1; }
        else         { Asrc = A2; kl = kc - K1; ldA = Ktot - K1; }
        {
            const float4* src = (const float4*)&Asrc[(size_t)(bm + ar)*ldA + kl + ah*16];
            *(float4*)&As[ar*40 + ah*16]     = src[0];
            *(float4*)&As[ar*40 + ah*16 + 8] = src[1];
        }
        *(float4*)&Bs[br*40 + bq*8] = *(const float4*)&Bt[(size_t)(bn + br)*Ktot + kc + bq*8];
        __syncthreads();
        half8 af[4], bf[2];
#pragma unroll
        for (int mt = 0; mt < 4; ++mt) af[mt] = *(half8*)&As[(wm + mt*16 + m16)*40 + kq*8];
#pragma unroll
        for (int nt = 0; nt < 2; ++nt) bf[nt] = *(half8*)&Bs[(wn + nt*16 + m16)*40 + kq*8];
#pragma unroll
        for (int mt = 0; mt < 4; ++mt)
#pragma unroll
            for (int nt = 0; nt < 2; ++nt)
                acc[mt][nt] = __builtin_amdgcn_mfma_f32_16x16x32_f16(af[mt], bf[nt], acc[mt][nt], 0, 0, 0);
        __syncthreads();
    }

#pragma unroll
    for (int mt = 0; mt < 4; ++mt) {
#pragma unroll
        for (int nt = 0; nt < 2; ++nt) {
            int col = bn + wn + nt*16 + m16;
#pragma unroll
            for (int r = 0; r < 4; ++r) {
                int row = bm + wm + mt*16 + kq*4 + r;
                float v = acc[mt][nt][r];
                if (EPI == 0) {
                    v = silu_f(v + bias[col]);
                } else if (EPI == 1) {
                    v = fmaf(v + bias[col], film[col], film[NC + col]);
                    v = silu_f(v);
                    if (addSkip) v += (float)h0[(size_t)row*NC + col];
                } else {
                    v += (float)h0[(size_t)row*NC + col];
                }
                C[(size_t)row*NC + col] = (_Float16)v;
            }
        }
    }
}

// ---------------- output head: (h @ W_out + b_out) * 0.01 ----------------
__global__ __launch_bounds__(256) void out_kernel(const _Float16* __restrict__ h,
                                                  const float* __restrict__ W_out,
                                                  const float* __restrict__ b_out,
                                                  float* __restrict__ out) {
    const int n = blockIdx.x * 256 + threadIdx.x;
    float a0 = 0.f, a1 = 0.f, a2 = 0.f;
#pragma unroll 4
    for (int k8 = 0; k8 < WIDTH/8; ++k8) {
        half8 v = *(const half8*)&h[(size_t)n*WIDTH + k8*8];
#pragma unroll
        for (int u = 0; u < 8; ++u) {
            float f = (float)v[u]; int k = k8*8 + u;
            a0 = fmaf(f, W_out[k*3+0], a0);
            a1 = fmaf(f, W_out[k*3+1], a1);
            a2 = fmaf(f, W_out[k*3+2], a2);
        }
    }
    out[n*3+0] = (a0 + b_out[0]) * 0.01f;
    out[n*3+1] = (a1 + b_out[1]) * 0.01f;
    out[n*3+2] = (a2 + b_out[2]) * 0.01f;
}

extern "C" void kernel_launch(void* const* d_in, const int* in_sizes, int n_in,
                              void* d_out, int out_size, void* d_ws, size_t ws_size,
                              hipStream_t stream) {
    const float* x      = (const float*)d_in[0];
    const float* cond   = (const float*)d_in[1];
    const float* Bf     = (const float*)d_in[2];
    const float* W_in   = (const float*)d_in[3];
    const float* b_in   = (const float*)d_in[4];
    const float* Wg_in  = (const float*)d_in[5];
    const float* bg_in  = (const float*)d_in[6];
    const float* Ws     = (const float*)d_in[7];
    const float* Wn     = (const float*)d_in[8];
    const float* bg     = (const float*)d_in[9];
    const float* Wg_out = (const float*)d_in[10];
    const float* W      = (const float*)d_in[11];
    const float* bmlp   = (const float*)d_in[12];
    const float* Wf_g   = (const float*)d_in[13];
    const float* bf_g   = (const float*)d_in[14];
    const float* Wf_b   = (const float*)d_in[15];
    const float* bf_b   = (const float*)d_in[16];
    const float* W_out  = (const float*)d_in[17];
    const float* b_out  = (const float*)d_in[18];
    float* out = (float*)d_out;

    char* ws = (char*)d_ws;
    int*       knn_idx = (int*)      (ws + 0);          //  3,145,728
    float4*    xw      = (float4*)   (ws + 3145728);    //  1,048,576
    float*     film    = (float*)    (ws + 4194304);    //     14,336
    _Float16*  Bg_t    = (_Float16*) (ws + 4210688);    //    589,824
    _Float16*  Wgo_t   = (_Float16*) (ws + 4800512);    //     98,304
    _Float16*  Wt      = (_Float16*) (ws + 4898816);    //    917,504
    _Float16*  h0      = (_Float16*) (ws + 5816320);    // 33,554,432 (f16)
    // SAT + seed overlay h0 region (dead before fourier_input writes h0)
    int*       cnt     = (int*)      (ws + 5816320);    // 28,311,552 (192^3 SAT in place)
    float*     seed    = (float*)    (ws + 34127872);   //    262,144 -> 34,390,016 < h0 end
    _Float16*  g_a     = (_Float16*) (ws + 39370752);   // 25,165,824
    // pd/pi overlay g_a (dead before fourier_input writes g_a)
    float*     pd      = (float*)    (ws + 39370752);   // 12,582,912
    int*       pi      = (int*)      (ws + 51953664);   // 12,582,912 -> 64,536,576 exact
    _Float16*  g_b     = (_Float16*) (ws + 64536576);   // 25,165,824
    _Float16*  agg     = (_Float16*) (ws + 89702400);   // 25,165,824
    _Float16*  hA      = (_Float16*) (ws + 114868224);  // 33,554,432
    _Float16*  hB      = (_Float16*) (ws + 148422656);  // 33,554,432 -> ends 181,977,088

    // --- kNN: SAT seed + seeded brute force ---
    prep_xw_kernel<<<NN/256, 256, 0, stream>>>(x, xw);
    zero_cnt_kernel<<<GC3/1024, 256, 0, stream>>>(cnt);
    hist_kernel<<<NN/256, 256, 0, stream>>>(xw, cnt);
    satx_kernel<<<GC*GC/256, 256, 0, stream>>>(cnt);
    saty_kernel<<<GC*GC/256, 256, 0, stream>>>(cnt);
    satz_kernel<<<GC*GC/256, 256, 0, stream>>>(cnt);
    seed_kernel<<<NN/256, 256, 0, stream>>>(xw, cnt, seed);
    knn_part_kernel<<<dim3(NN/256, KSEG), 256, 0, stream>>>(xw, seed, pd, pi);
    knn_merge_kernel<<<NN/256, 256, 0, stream>>>(pd, pi, knn_idx);

    // --- network ---
    film_kernel<<<DEPTH, 256, 0, stream>>>(cond, Wf_g, bf_g, Wf_b, bf_b, film);
    convert_Wt_kernel<<<DEPTH*65536/256, 256, 0, stream>>>(W, Wt);
    convert_Bg_kernel<<<GLAYERS*73728/256, 256, 0, stream>>>(Ws, Wn, Bg_t);
    convert_Wgo_kernel<<<256*192/256, 256, 0, stream>>>(Wg_out, Wgo_t);
    fourier_input_kernel<<<NN/256, 256, 0, stream>>>(x, Bf, W_in, b_in, Wg_in, bg_in, h0, g_a);

    _Float16* gin = g_a; _Float16* gout = g_b;
    for (int l = 0; l < GLAYERS; ++l) {
        gather_mean_kernel<<<NN, GW, 0, stream>>>(gin, knn_idx, agg);
        gemm_mfma<0><<<dim3(NN/128, GW/64), 256, 0, stream>>>(
            gin, agg, Bg_t + (size_t)l*73728, GW, 2*GW, GW,
            bg + l*GW, nullptr, nullptr, gout, 0);
        _Float16* t = gin; gin = gout; gout = t;
    }
    // gin == g_a (4 swaps). inject: hA = h0 + gin @ Wg_out
    gemm_mfma<2><<<dim3(NN/128, WIDTH/64), 256, 0, stream>>>(
        gin, nullptr, Wgo_t, GW, GW, WIDTH, nullptr, nullptr, h0, hA, 0);

    _Float16* hin = hA; _Float16* hout = hB;
    for (int l = 0; l < DEPTH; ++l) {
        int skip = (l == 2 || l == 5) ? 1 : 0;   // SKIPS=(3,6): after layers idx 2,5
        gemm_mfma<1><<<dim3(NN/128, WIDTH/64), 256, 0, stream>>>(
            hin, nullptr, Wt + (size_t)l*65536, WIDTH, WIDTH, WIDTH,
            bmlp + l*WIDTH, film + l*2*WIDTH, h0, hout, skip);
        _Float16* t = hin; hin = hout; hout = t;
    }
    out_kernel<<<NN/256, 256, 0, stream>>>(hin, W_out, b_out, out);
}